// Round 6
// baseline (564.303 us; speedup 1.0000x reference)
//
#include <hip/hip_runtime.h>

// SpatialEvoProp — R6: LDS-free k_edge. R5 showed block-shape changes make
// the allocator spill (VGPR 64, +340 MB scratch traffic); the only clean
// codegen point is 256thr/(256,3) -> VGPR 84, no spill. There, occupancy was
// LDS-capped (50.7KB -> 12 waves/CU). Fix: move P and the bf16 W-fragments
// to d_ws (precomputed in k_init), k_edge reads them via L1/L2-resident
// global loads -> LDS=0 -> VGPR-capped occupancy 24 waves/CU. Work-stealing
// group distribution (atomicAdd batch=4) removes tail imbalance.

#define DFEAT 64

typedef __attribute__((ext_vector_type(8))) short short8;
typedef __attribute__((ext_vector_type(4))) float floatx4;

__device__ __forceinline__ short bf16h(float x) {
    unsigned u = __float_as_uint(x);
    return (short)((u + 0x7FFFu + ((u >> 16) & 1u)) >> 16);
}
__device__ __forceinline__ float bf16tof(short h) {
    return __uint_as_float(((unsigned)(unsigned short)h) << 16);
}

// count(boundaries < x): analytic seed + shuffle-verified walk against the
// real table values (lane L holds boundaries[L]); exact (verified R3).
__device__ __forceinline__ int bucketize(float x, float bnd) {
    int i = (int)(x * 31.5f);
    i = min(max(i, 0), 64);
#pragma unroll
    for (int t = 0; t < 3; ++t) {
        float bi = __shfl(bnd, min(i, 63));
        if (i < 64 && bi < x) ++i;
    }
#pragma unroll
    for (int t = 0; t < 2; ++t) {
        float bim = __shfl(bnd, max(i - 1, 0));
        if (i > 0 && bim >= x) --i;
    }
    return i;
}

// zero rst/degs/ctr, compute P = embed @ G_w.T, build bf16 hi/lo B-frags
__global__ void k_init(const float* __restrict__ Etab,
                       const float* __restrict__ G,
                       const float* __restrict__ agg_w,
                       float* __restrict__ P, short8* __restrict__ Bh,
                       short8* __restrict__ Bl, int* __restrict__ ctr,
                       float* __restrict__ rst, float* __restrict__ degs,
                       int nRst4, int nDeg) {
    int i = blockIdx.x * blockDim.x + threadIdx.x;
    if (i < nRst4) ((floatx4*)rst)[i] = (floatx4){0.f, 0.f, 0.f, 0.f};
    if (i < nDeg) degs[i] = 0.0f;
    if (i == 0) *ctr = 0;
    if (i < 65 * DFEAT) {
        int b = i >> 6, o = i & 63;
        float a = 0.0f;
#pragma unroll
        for (int m = 0; m < 32; ++m)
            a = fmaf(Etab[b * 32 + m], G[o * 32 + m], a);
        P[i] = a;
    }
    if (i < 16 * 64) {  // frag f = sl*4+nt; lane l: n=nt*16+(l&15), k=sl*32+(l>>4)*8+j
        int f = i >> 6, l = i & 63;
        int sl = f >> 2, nt = f & 3;
        const float* wp =
            agg_w + (nt * 16 + (l & 15)) * 128 + sl * 32 + (l >> 4) * 8;
        short8 h, lo;
#pragma unroll
        for (int j = 0; j < 8; ++j) {
            float x = wp[j];
            short hh = bf16h(x);
            h[j] = hh;
            lo[j] = bf16h(x - bf16tof(hh));
        }
        Bh[i] = h;
        Bl[i] = lo;
    }
}

__global__ void k_deg(const int* __restrict__ src, const int* __restrict__ dst,
                      float* __restrict__ degs, int N, int E) {
    int i = blockIdx.x * blockDim.x + threadIdx.x;
    if (i < E) {
        atomicAdd(&degs[dst[i]], 1.0f);
        atomicAdd(&degs[N + src[i]], 1.0f);
    }
}

__global__ __launch_bounds__(256, 3) void k_edge(
    const float* __restrict__ feat, const float* __restrict__ loc,
    const float* __restrict__ agg_b, const float* __restrict__ bnds,
    const int* __restrict__ src, const int* __restrict__ dst,
    const int* __restrict__ inter, const float* __restrict__ P,
    const short8* __restrict__ Bh, const short8* __restrict__ Bl,
    const float* __restrict__ degs, int* __restrict__ ctr,
    float* __restrict__ rst, int N, int E) {
    const int lane = threadIdx.x & 63;
    const int m16 = lane & 15;
    const int quad = lane >> 4;

    const float bnd = bnds[lane];
    float bias4[4];
#pragma unroll
    for (int nt = 0; nt < 4; ++nt) bias4[nt] = agg_b[nt * 16 + m16];

    const int ngroups = (E + 15) >> 4;

    while (true) {
        int base;
        if (lane == 0) base = atomicAdd(ctr, 4);  // claim 4 groups
        base = __shfl(base, 0);
        if (base >= ngroups) break;
        const int gend = min(base + 4, ngroups);

        for (int g = base; g < gend; ++g) {
            const int em = (g << 4) + m16;
            const bool act = em < E;
            const int ec = act ? em : 0;

            const int s = src[ec];
            const int d = dst[ec];
            const float2 ls = ((const float2*)loc)[s];
            const float2 ld = ((const float2*)loc)[d];
            float dsc = rsqrtf(fmaxf(degs[d], 1.0f)) *
                        rsqrtf(fmaxf(degs[N + s], 1.0f));
            if (!act) dsc = 0.0f;

            float dx = ld.x - ls.x, dy = ld.y - ls.y;
            const int b1 = bucketize(sqrtf(dx * dx + dy * dy), bnd);

            int ij[5], bj[5];
#pragma unroll
            for (int j = 0; j < 5; ++j) {
                int id = inter[ec * 5 + j];
                ij[j] = id;
                float2 lj = ((const float2*)loc)[id];
                float ex = ls.x - lj.x, ey = ls.y - lj.y;
                bj[j] = bucketize(sqrtf(ex * ex + ey * ey), bnd);
            }

            // ---- A fragments in registers ---------------------------------
            short8 Ah[4], Al[4];
            {
                const float* frow = feat + (s << 6);
                const float* prow = P + (b1 << 6);
#pragma unroll
                for (int sl = 0; sl < 2; ++sl) {  // u: cat[k<64]
                    int k0 = sl * 32 + quad * 8;
                    floatx4 fa = *(const floatx4*)(frow + k0);
                    floatx4 fb = *(const floatx4*)(frow + k0 + 4);
                    floatx4 pa = *(const floatx4*)(prow + k0);
                    floatx4 pb = *(const floatx4*)(prow + k0 + 4);
                    float xs[8] = {fa.x * pa.x, fa.y * pa.y, fa.z * pa.z,
                                   fa.w * pa.w, fb.x * pb.x, fb.y * pb.y,
                                   fb.z * pb.z, fb.w * pb.w};
                    short8 h, l;
#pragma unroll
                    for (int j = 0; j < 8; ++j) {
                        short hh = bf16h(xs[j]);
                        h[j] = hh;
                        l[j] = bf16h(xs[j] - bf16tof(hh));
                    }
                    Ah[sl] = h;
                    Al[sl] = l;
                }
            }
#pragma unroll
            for (int sl = 0; sl < 2; ++sl) {  // v: cat[k>=64]
                int k0 = sl * 32 + quad * 8;
                float r[8] = {0, 0, 0, 0, 0, 0, 0, 0};
#pragma unroll
                for (int j = 0; j < 5; ++j) {
                    const float* fr = feat + (ij[j] << 6);
                    const float* pr = P + (bj[j] << 6);
                    floatx4 fa = *(const floatx4*)(fr + k0);
                    floatx4 fb = *(const floatx4*)(fr + k0 + 4);
                    floatx4 pa = *(const floatx4*)(pr + k0);
                    floatx4 pb = *(const floatx4*)(pr + k0 + 4);
                    r[0] = fmaf(fa.x, pa.x, r[0]);
                    r[1] = fmaf(fa.y, pa.y, r[1]);
                    r[2] = fmaf(fa.z, pa.z, r[2]);
                    r[3] = fmaf(fa.w, pa.w, r[3]);
                    r[4] = fmaf(fb.x, pb.x, r[4]);
                    r[5] = fmaf(fb.y, pb.y, r[5]);
                    r[6] = fmaf(fb.z, pb.z, r[6]);
                    r[7] = fmaf(fb.w, pb.w, r[7]);
                }
                short8 h, l;
#pragma unroll
                for (int j = 0; j < 8; ++j) {
                    float x = r[j] * 0.2f;
                    short hh = bf16h(x);
                    h[j] = hh;
                    l[j] = bf16h(x - bf16tof(hh));
                }
                Ah[2 + sl] = h;
                Al[2 + sl] = l;
            }

            // ---- MFMA: 4 k-slabs x 4 n-tiles x 3 products -----------------
            floatx4 acc[4] = {
                {0, 0, 0, 0}, {0, 0, 0, 0}, {0, 0, 0, 0}, {0, 0, 0, 0}};
#pragma unroll
            for (int sl = 0; sl < 4; ++sl) {
#pragma unroll
                for (int nt = 0; nt < 4; ++nt) {
                    short8 bh = Bh[((sl << 2) + nt) * 64 + lane];
                    short8 bl = Bl[((sl << 2) + nt) * 64 + lane];
                    acc[nt] = __builtin_amdgcn_mfma_f32_16x16x32_bf16(
                        Ah[sl], bh, acc[nt], 0, 0, 0);
                    acc[nt] = __builtin_amdgcn_mfma_f32_16x16x32_bf16(
                        Al[sl], bh, acc[nt], 0, 0, 0);
                    acc[nt] = __builtin_amdgcn_mfma_f32_16x16x32_bf16(
                        Ah[sl], bl, acc[nt], 0, 0, 0);
                }
            }

            // ---- epilogue: C row=quad*4+r (edge), col=nt*16+m16 (feature) -
#pragma unroll
            for (int r = 0; r < 4; ++r) {
                const int m = (quad << 2) + r;
                const int dm = __shfl(d, m);
                const float sc = __shfl(dsc, m);
#pragma unroll
                for (int nt = 0; nt < 4; ++nt) {
                    float val = (acc[nt][r] + bias4[nt]) * sc;
                    atomicAdd(&rst[(dm << 6) + nt * 16 + m16], val);
                }
            }
        }
    }
}

extern "C" void kernel_launch(void* const* d_in, const int* in_sizes, int n_in,
                              void* d_out, int out_size, void* d_ws,
                              size_t ws_size, hipStream_t stream) {
    const float* feat  = (const float*)d_in[0];
    const float* loc   = (const float*)d_in[1];
    const float* embed = (const float*)d_in[2];
    const float* G_w   = (const float*)d_in[3];
    const float* agg_w = (const float*)d_in[4];
    const float* agg_b = (const float*)d_in[5];
    const float* bnds  = (const float*)d_in[6];
    const int* src   = (const int*)d_in[7];
    const int* dst   = (const int*)d_in[8];
    const int* inter = (const int*)d_in[9];

    const int N = in_sizes[0] / DFEAT;
    const int E = in_sizes[7];

    float* rst = (float*)d_out;
    float* ws = (float*)d_ws;
    // ws layout (16B-aligned at every boundary):
    float* degs = ws;                          // [2N]
    float* P = ws + 2 * (size_t)N;             // [65*64]
    short8* Bh = (short8*)(P + 65 * DFEAT);    // [16*64] x 16B
    short8* Bl = Bh + 16 * 64;                 // [16*64] x 16B
    int* ctr = (int*)(Bl + 16 * 64);           // [1]

    const int nRst4 = N * DFEAT / 4;
    const int nDeg = 2 * N;

    k_init<<<(nRst4 + 255) / 256, 256, 0, stream>>>(embed, G_w, agg_w, P, Bh,
                                                    Bl, ctr, rst, degs, nRst4,
                                                    nDeg);
    k_deg<<<(E + 255) / 256, 256, 0, stream>>>(src, dst, degs, N, E);
    // LDS-free: occupancy VGPR-capped (84 -> 6 waves/EU = 24 waves/CU).
    // 1536 blocks = 6 blocks/CU resident; work-stealing balances the tail.
    k_edge<<<1536, 256, 0, stream>>>(feat, loc, agg_b, bnds, src, dst, inter,
                                     P, Bh, Bl, degs, ctr, rst, N, E);
}

// Round 7
// 336.850 us; speedup vs baseline: 1.6752x; 1.6752x over previous
//
#include <hip/hip_runtime.h>

// SpatialEvoProp — R7: R3's known-good memory structure (sP + W-frags in
// LDS, 256thr, grid 768) + amdgpu_waves_per_eu(3,3). Root cause R1-R6: the
// allocator targets 6 waves/EU (84 VGPRs) on its own, but R3's HW occupancy
// is LDS-capped at 3 waves/EU — so it serialized ~7 gather epochs/group.
// (3,3) licenses ~170 VGPRs at the occupancy we actually get; the A-build is
// restructured to issue ALL 24 feat float4 loads (96 regs) right after the
// index epoch, bucketize under their latency, then read LDS-resident sP.
// Critical path: 7 global epochs -> 2.

#define DFEAT 64
#define PPAD 68  // sP row stride (floats)

typedef __attribute__((ext_vector_type(8))) short short8;
typedef __attribute__((ext_vector_type(4))) float floatx4;

__device__ __forceinline__ short bf16h(float x) {
    unsigned u = __float_as_uint(x);
    return (short)((u + 0x7FFFu + ((u >> 16) & 1u)) >> 16);
}
__device__ __forceinline__ float bf16tof(short h) {
    return __uint_as_float(((unsigned)(unsigned short)h) << 16);
}
__device__ __forceinline__ void split8(const float* xs, short8& h, short8& l) {
#pragma unroll
    for (int j = 0; j < 8; ++j) {
        short hh = bf16h(xs[j]);
        h[j] = hh;
        l[j] = bf16h(xs[j] - bf16tof(hh));
    }
}

// count(boundaries < x): analytic seed + shuffle-verified walk against the
// real table values (lane L holds boundaries[L]); exact (verified R3).
__device__ __forceinline__ int bucketize(float x, float bnd) {
    int i = (int)(x * 31.5f);
    i = min(max(i, 0), 64);
#pragma unroll
    for (int t = 0; t < 3; ++t) {
        float bi = __shfl(bnd, min(i, 63));
        if (i < 64 && bi < x) ++i;
    }
#pragma unroll
    for (int t = 0; t < 2; ++t) {
        float bim = __shfl(bnd, max(i - 1, 0));
        if (i > 0 && bim >= x) --i;
    }
    return i;
}

__global__ void k_zero(float* __restrict__ rst, float* __restrict__ degs,
                       int nRst4, int nDeg) {
    int i = blockIdx.x * blockDim.x + threadIdx.x;
    if (i < nRst4) ((floatx4*)rst)[i] = (floatx4){0.f, 0.f, 0.f, 0.f};
    if (i < nDeg) degs[i] = 0.0f;
}

__global__ void k_deg(const int* __restrict__ src, const int* __restrict__ dst,
                      float* __restrict__ degs, int N, int E) {
    int i = blockIdx.x * blockDim.x + threadIdx.x;
    if (i < E) {
        atomicAdd(&degs[dst[i]], 1.0f);
        atomicAdd(&degs[N + src[i]], 1.0f);
    }
}

__global__ __attribute__((amdgpu_flat_work_group_size(256, 256),
                          amdgpu_waves_per_eu(3, 3))) void k_edge(
    const float* __restrict__ feat, const float* __restrict__ loc,
    const float* __restrict__ Etab, const float* __restrict__ G,
    const float* __restrict__ agg_w, const float* __restrict__ agg_b,
    const float* __restrict__ bnds, const int* __restrict__ src,
    const int* __restrict__ dst, const int* __restrict__ inter,
    const float* __restrict__ degs, float* __restrict__ rst, int N, int E) {
    const int tid = threadIdx.x;
    const int lane = tid & 63;
    const int wid = tid >> 6;
    const int m16 = lane & 15;
    const int quad = lane >> 4;

    __shared__ alignas(16) float sP[65 * PPAD];  // 17680 B
    __shared__ short8 sWBh[16 * 64];             // 16384 B
    __shared__ short8 sWBl[16 * 64];             // 16384 B

    // per-block P = embed @ G_w.T (520 fma/lane, once)
    for (int i = tid; i < 65 * DFEAT; i += 256) {
        int b = i >> 6, o = i & 63;
        float a = 0.0f;
#pragma unroll
        for (int m = 0; m < 32; ++m)
            a = fmaf(Etab[b * 32 + m], G[o * 32 + m], a);
        sP[b * PPAD + o] = a;
    }

    // B-frag f = slab*4+ntile; lane holds n = nt*16+m16, k = sl*32+quad*8+j
    for (int f = wid; f < 16; f += 4) {
        int sl = f >> 2, nt = f & 3;
        const float* wp = agg_w + (nt * 16 + m16) * 128 + sl * 32 + quad * 8;
        float xs[8];
#pragma unroll
        for (int j = 0; j < 8; ++j) xs[j] = wp[j];
        short8 h, l;
        split8(xs, h, l);
        sWBh[f * 64 + lane] = h;
        sWBl[f * 64 + lane] = l;
    }

    const float bnd = bnds[lane];
    float bias4[4];
#pragma unroll
    for (int nt = 0; nt < 4; ++nt) bias4[nt] = agg_b[nt * 16 + m16];

    __syncthreads();

    const int nstream = gridDim.x << 2;
    const int wstream = (blockIdx.x << 2) + wid;
    const int ngroups = (E + 15) >> 4;
    const int o0 = quad * 8;        // slab0 k-offset for this lane
    const int o1 = 32 + quad * 8;   // slab1 k-offset

    for (int g = wstream; g < ngroups; g += nstream) {
        const int em = (g << 4) + m16;
        const bool act = em < E;
        const int ec = act ? em : 0;

        // -- epoch 1: indices ----------------------------------------------
        const int s = src[ec];
        const int d = dst[ec];
        int ij[5];
#pragma unroll
        for (int j = 0; j < 5; ++j) ij[j] = inter[ec * 5 + j];

        // -- epoch 2: loc + degs + ALL feat rows (24 float4, independent) --
        const float2 ls = ((const float2*)loc)[s];
        const float2 ld = ((const float2*)loc)[d];
        float2 lj[5];
#pragma unroll
        for (int j = 0; j < 5; ++j) lj[j] = ((const float2*)loc)[ij[j]];
        float dsc = rsqrtf(fmaxf(degs[d], 1.0f)) *
                    rsqrtf(fmaxf(degs[N + s], 1.0f));
        if (!act) dsc = 0.0f;

        floatx4 F[24];  // row r (0=src,1..5=inter j): F[4r..4r+3] =
                        // {slab0 k0, slab0 k0+4, slab1 k0, slab1 k0+4}
        {
            const float* fr = feat + (s << 6);
            F[0] = *(const floatx4*)(fr + o0);
            F[1] = *(const floatx4*)(fr + o0 + 4);
            F[2] = *(const floatx4*)(fr + o1);
            F[3] = *(const floatx4*)(fr + o1 + 4);
        }
#pragma unroll
        for (int j = 0; j < 5; ++j) {
            const float* fr = feat + (ij[j] << 6);
            F[4 + 4 * j + 0] = *(const floatx4*)(fr + o0);
            F[4 + 4 * j + 1] = *(const floatx4*)(fr + o0 + 4);
            F[4 + 4 * j + 2] = *(const floatx4*)(fr + o1);
            F[4 + 4 * j + 3] = *(const floatx4*)(fr + o1 + 4);
        }

        // -- bucketize (pure shuffles; overlaps feat-load latency) ---------
        float dx = ld.x - ls.x, dy = ld.y - ls.y;
        const int b1 = bucketize(sqrtf(dx * dx + dy * dy), bnd);
        int bj[5];
#pragma unroll
        for (int j = 0; j < 5; ++j) {
            float ex = ls.x - lj[j].x, ey = ls.y - lj[j].y;
            bj[j] = bucketize(sqrtf(ex * ex + ey * ey), bnd);
        }

        // -- A fragments: products vs LDS-resident sP ----------------------
        short8 Ah[4], Al[4];
        {
            const float* prow = sP + b1 * PPAD;
#pragma unroll
            for (int sl = 0; sl < 2; ++sl) {  // u: cat[k<64]
                const int k0 = sl * 32 + o0 - sl * 8 * 0;  // = sl?o1:o0
                const float* pp = prow + (sl ? o1 : o0);
                floatx4 pa = *(const floatx4*)pp;
                floatx4 pb = *(const floatx4*)(pp + 4);
                const floatx4 fa = F[2 * sl];
                const floatx4 fb = F[2 * sl + 1];
                float xs[8] = {fa.x * pa.x, fa.y * pa.y, fa.z * pa.z,
                               fa.w * pa.w, fb.x * pb.x, fb.y * pb.y,
                               fb.z * pb.z, fb.w * pb.w};
                split8(xs, Ah[sl], Al[sl]);
                (void)k0;
            }
        }
#pragma unroll
        for (int sl = 0; sl < 2; ++sl) {  // v: cat[k>=64]
            float r[8] = {0, 0, 0, 0, 0, 0, 0, 0};
#pragma unroll
            for (int j = 0; j < 5; ++j) {
                const float* pp = sP + bj[j] * PPAD + (sl ? o1 : o0);
                floatx4 pa = *(const floatx4*)pp;
                floatx4 pb = *(const floatx4*)(pp + 4);
                const floatx4 fa = F[4 + 4 * j + 2 * sl];
                const floatx4 fb = F[4 + 4 * j + 2 * sl + 1];
                r[0] = fmaf(fa.x, pa.x, r[0]);
                r[1] = fmaf(fa.y, pa.y, r[1]);
                r[2] = fmaf(fa.z, pa.z, r[2]);
                r[3] = fmaf(fa.w, pa.w, r[3]);
                r[4] = fmaf(fb.x, pb.x, r[4]);
                r[5] = fmaf(fb.y, pb.y, r[5]);
                r[6] = fmaf(fb.z, pb.z, r[6]);
                r[7] = fmaf(fb.w, pb.w, r[7]);
            }
            float xs[8];
#pragma unroll
            for (int j = 0; j < 8; ++j) xs[j] = r[j] * 0.2f;
            split8(xs, Ah[2 + sl], Al[2 + sl]);
        }

        // -- MFMA: 4 k-slabs x 4 n-tiles x 3 products ----------------------
        floatx4 acc[4] = {
            {0, 0, 0, 0}, {0, 0, 0, 0}, {0, 0, 0, 0}, {0, 0, 0, 0}};
#pragma unroll
        for (int sl = 0; sl < 4; ++sl) {
#pragma unroll
            for (int nt = 0; nt < 4; ++nt) {
                short8 bh = sWBh[((sl << 2) + nt) * 64 + lane];
                short8 bl = sWBl[((sl << 2) + nt) * 64 + lane];
                acc[nt] = __builtin_amdgcn_mfma_f32_16x16x32_bf16(
                    Ah[sl], bh, acc[nt], 0, 0, 0);
                acc[nt] = __builtin_amdgcn_mfma_f32_16x16x32_bf16(
                    Al[sl], bh, acc[nt], 0, 0, 0);
                acc[nt] = __builtin_amdgcn_mfma_f32_16x16x32_bf16(
                    Ah[sl], bl, acc[nt], 0, 0, 0);
            }
        }

        // -- epilogue: C row = quad*4+r (edge), col = nt*16+m16 (feature) --
#pragma unroll
        for (int r = 0; r < 4; ++r) {
            const int m = (quad << 2) + r;
            const int dm = __shfl(d, m);
            const float sc = __shfl(dsc, m);
#pragma unroll
            for (int nt = 0; nt < 4; ++nt) {
                float val = (acc[nt][r] + bias4[nt]) * sc;
                atomicAdd(&rst[(dm << 6) + nt * 16 + m16], val);
            }
        }
    }
}

extern "C" void kernel_launch(void* const* d_in, const int* in_sizes, int n_in,
                              void* d_out, int out_size, void* d_ws,
                              size_t ws_size, hipStream_t stream) {
    const float* feat  = (const float*)d_in[0];
    const float* loc   = (const float*)d_in[1];
    const float* embed = (const float*)d_in[2];
    const float* G_w   = (const float*)d_in[3];
    const float* agg_w = (const float*)d_in[4];
    const float* agg_b = (const float*)d_in[5];
    const float* bnds  = (const float*)d_in[6];
    const int* src   = (const int*)d_in[7];
    const int* dst   = (const int*)d_in[8];
    const int* inter = (const int*)d_in[9];

    const int N = in_sizes[0] / DFEAT;
    const int E = in_sizes[7];

    float* rst = (float*)d_out;
    float* degs = (float*)d_ws;  // [2N]: [0,N)=in-deg, [N,2N)=out-deg

    const int nRst4 = N * DFEAT / 4;
    const int nDeg = 2 * N;

    k_zero<<<(nRst4 + 255) / 256, 256, 0, stream>>>(rst, degs, nRst4, nDeg);
    k_deg<<<(E + 255) / 256, 256, 0, stream>>>(src, dst, degs, N, E);
    // LDS 50448 B -> 3 blocks/CU = 12 waves/CU; waves_per_eu(3,3) aligns the
    // register allocator with that reality (~170 VGPR budget, no spill).
    k_edge<<<768, 256, 0, stream>>>(feat, loc, embed, G_w, agg_w, agg_b, bnds,
                                    src, dst, inter, degs, rst, N, E);
}